// Round 7
// baseline (138.142 us; speedup 1.0000x reference)
//
#include <hip/hip_runtime.h>

// Problem constants
#define MD 4
#define DD 9            // 2*MD+1
#define B  4
#define C  64
#define H  64
#define W  128
#define HW (H * W)      // 8192 floats per (i,j) slice of one (b,c)

// Zero-padded LDS tile: 4 border rows/cols each side, row stride 136 words
#define LROW  136
#define LROWS 72
#define LDSW  (LROWS * LROW)   // 9792 words = 39168 B -> 4 blocks/CU

typedef float f32x4 __attribute__((ext_vector_type(4)));

__device__ __forceinline__ f32x4 lrelu4(f32x4 p) {
    f32x4 o;
    o.x = fmaxf(p.x, 0.1f * p.x);
    o.y = fmaxf(p.y, 0.1f * p.y);
    o.z = fmaxf(p.z, 0.1f * p.z);
    o.w = fmaxf(p.w, 0.1f * p.w);
    return o;
}

// Hot loop: LDS reads + linear stores ONLY (no global loads -> store queue
// never drains on vmcnt). d = I-4 is compile-time: window extract is a free
// static register pick from 1-2 aligned ds_read_b128.
template<int I>
__device__ __forceinline__ void compute_i(const float* __restrict__ ldsT,
                                          const f32x4* r8,
                                          float* __restrict__ outu,
                                          unsigned x4, unsigned yw) {
    constexpr int d = I - MD;   // -4..4
    const unsigned x = x4 * 4u;

    #pragma unroll
    for (int j = 0; j < DD; ++j) {
        float* oj = outu + (size_t)j * HW;
        #pragma unroll
        for (int s = 0; s < 8; ++s) {
            const unsigned y    = (unsigned)s * 8u + yw;
            const unsigned rowb = (y + (unsigned)j) * LROW;  // lds row = ty+4
            f32x4 t;
            if constexpr (d == 0) {
                t = *reinterpret_cast<const f32x4*>(ldsT + rowb + 4u + x);
            } else if constexpr (d < 0) {
                const f32x4 m = *reinterpret_cast<const f32x4*>(ldsT + rowb + x);
                const f32x4 c = *reinterpret_cast<const f32x4*>(ldsT + rowb + 4u + x);
                const float tw[8] = {m.x, m.y, m.z, m.w, c.x, c.y, c.z, c.w};
                t = (f32x4){tw[4 + d], tw[5 + d], tw[6 + d], tw[7 + d]};
            } else {
                const f32x4 c = *reinterpret_cast<const f32x4*>(ldsT + rowb + 4u + x);
                const f32x4 p = *reinterpret_cast<const f32x4*>(ldsT + rowb + 8u + x);
                const float tw[8] = {c.x, c.y, c.z, c.w, p.x, p.y, p.z, p.w};
                t = (f32x4){tw[d], tw[d + 1], tw[d + 2], tw[d + 3]};
            }
            *reinterpret_cast<f32x4*>(oj + (size_t)y * W + x) = lrelu4(r8[s] * t);
        }
    }
}

__global__ __launch_bounds__(256) void corr_kernel(const float* __restrict__ ref,
                                                   const float* __restrict__ tgt,
                                                   float* __restrict__ out) {
    __shared__ __align__(16) float ldsT[LDSW];

    const unsigned t  = threadIdx.x;
    const unsigned bc = blockIdx.x / 9u;          // magic-mul
    const unsigned i  = blockIdx.x - bc * 9u;
    const unsigned x4 = t & 31u;
    const unsigned yw = t >> 5;                   // 0..7
    const unsigned x  = x4 * 4u;

    const float* refp = ref + (size_t)bc * HW;
    const float* tgtp = tgt + (size_t)bc * HW;

    // Zero borders (disjoint from data region -> single sync suffices)
    const f32x4 z4 = {0.f, 0.f, 0.f, 0.f};
    if (t < 136u) {
        reinterpret_cast<f32x4*>(ldsT)[t] = z4;                     // rows 0-3
        reinterpret_cast<f32x4*>(ldsT + 68 * LROW)[t] = z4;         // rows 68-71
    } else if (t < 200u) {
        const unsigned r = 4u + (t - 136u);                         // rows 4..67
        *reinterpret_cast<f32x4*>(ldsT + r * LROW) = z4;            // cols 0-3
        *reinterpret_cast<f32x4*>(ldsT + r * LROW + 132u) = z4;     // cols 132-135
    }

    // Stage data region: 2048 f4, 8 per thread, all 16B-aligned LDS writes
    #pragma unroll
    for (int z = 0; z < 8; ++z) {
        const unsigned idx = (unsigned)z * 256u + t;   // f4 index in plane
        const unsigned row = idx >> 5;                 // 0..63
        const unsigned c4  = idx & 31u;
        const f32x4 g = *reinterpret_cast<const f32x4*>(tgtp + (size_t)idx * 4u);
        *reinterpret_cast<f32x4*>(ldsT + (row + 4u) * LROW + 4u + c4 * 4u) = g;
    }

    // Ref stripe into registers (rows yw, 8+yw, ..., 56+yw)
    f32x4 r8[8];
    #pragma unroll
    for (int s = 0; s < 8; ++s)
        r8[s] = *reinterpret_cast<const f32x4*>(refp + (size_t)(s * 8 + yw) * W + x);

    __syncthreads();   // the only barrier in the block's lifetime

    float* outu = out + ((size_t)bc * (DD * DD) + (size_t)i * DD) * HW;
    switch (i) {
        case 0: compute_i<0>(ldsT, r8, outu, x4, yw); break;
        case 1: compute_i<1>(ldsT, r8, outu, x4, yw); break;
        case 2: compute_i<2>(ldsT, r8, outu, x4, yw); break;
        case 3: compute_i<3>(ldsT, r8, outu, x4, yw); break;
        case 4: compute_i<4>(ldsT, r8, outu, x4, yw); break;
        case 5: compute_i<5>(ldsT, r8, outu, x4, yw); break;
        case 6: compute_i<6>(ldsT, r8, outu, x4, yw); break;
        case 7: compute_i<7>(ldsT, r8, outu, x4, yw); break;
        default: compute_i<8>(ldsT, r8, outu, x4, yw); break;
    }
}

extern "C" void kernel_launch(void* const* d_in, const int* in_sizes, int n_in,
                              void* d_out, int out_size, void* d_ws, size_t ws_size,
                              hipStream_t stream) {
    const float* ref = (const float*)d_in[0];
    const float* tgt = (const float*)d_in[1];
    float* out = (float*)d_out;

    // 256 bc-planes x 9 i-values: each block writes one contiguous 288 KB
    // output unit sequentially ([j][y][x] order).
    corr_kernel<<<B * C * DD, 256, 0, stream>>>(ref, tgt, out);
}

// Round 8
// 131.980 us; speedup vs baseline: 1.0467x; 1.0467x over previous
//
#include <hip/hip_runtime.h>

// Problem constants
#define MD 4
#define DD 9          // 2*MD+1
#define B  4
#define C  64
#define H  64
#define W  128
#define W4 (W / 4)    // 32 float4 per row
#define HW (H * W)    // 8192 floats per (i,j) slice of one (b,c)

typedef float f32x4 __attribute__((ext_vector_type(4)));

// FINAL (revert to round-6 winner, 131.4 us):
// out[b][c][i][j][y][x] = leaky_relu(ref[b,c,y,x]*tgt[b,c,y+j-4,x+i-4]), 0 OOB.
//
// Structure: one thread per (b,c,y,x4), j-range split across 2 blocks so the
// whole tgt window fits registers. Load phase issues ALL window loads up
// front (one vmcnt wait while zero stores are outstanding), then a pure
// fire-and-forget store burst with no intervening waitcnt (loads and stores
// share vmcnt on CDNA; interleaving them forces store-queue drains).
//   jh=0: j=0..4  -> window rows ty=y-4..y   (15 f4 loads, 45 stores)
//   jh=1: j=5..8  -> window rows ty=y+1..y+4 (12 f4 loads, 36 stores)
// No LDS, no barriers. Measured: 5.2 TB/s effective write BW (vs 6.7 TB/s
// pure-fill reference); linear-write variants (rounds 3/4/7) all slower.

__device__ __forceinline__ float lrelu(float p) {
    return fmaxf(p, 0.1f * p);
}

template<int JSTART, int JCNT>
__device__ __forceinline__ void run_half(const float* __restrict__ refp,
                                         const float* __restrict__ tgtp,
                                         float* __restrict__ outb,  // + bc*81*HW
                                         unsigned y, unsigned x4) {
    const unsigned x = x4 * 4u;
    const bool has_m = (x4 > 0);
    const bool has_p = (x4 < W4 - 1);

    const f32x4 r = *reinterpret_cast<const f32x4*>(refp + (size_t)y * W + x);

    // ---- load phase: entire window into registers, zero-masked ----
    f32x4 win[JCNT][3];
    #pragma unroll
    for (int rr = 0; rr < JCNT; ++rr) {
        const int ty = (int)y + (JSTART + rr) - MD;
        const bool vrow = (ty >= 0) & (ty < H);
        const int tyc = ty < 0 ? 0 : (ty > H - 1 ? H - 1 : ty);
        const float* trow = tgtp + (size_t)tyc * W;
        f32x4 tm = *reinterpret_cast<const f32x4*>(trow + (has_m ? x - 4 : x));
        f32x4 tc = *reinterpret_cast<const f32x4*>(trow + x);
        f32x4 tp = *reinterpret_cast<const f32x4*>(trow + (has_p ? x + 4 : x));
        const float zm = (vrow & has_m) ? 1.f : 0.f;
        const float zc = vrow ? 1.f : 0.f;
        const float zp = (vrow & has_p) ? 1.f : 0.f;
        win[rr][0] = tm * zm;
        win[rr][1] = tc * zc;
        win[rr][2] = tp * zp;
    }

    // ---- store phase: pure burst, no loads, no waitcnt ----
    #pragma unroll
    for (int rr = 0; rr < JCNT; ++rr) {
        const int j = JSTART + rr;
        const float tw[12] = {win[rr][0].x, win[rr][0].y, win[rr][0].z, win[rr][0].w,
                              win[rr][1].x, win[rr][1].y, win[rr][1].z, win[rr][1].w,
                              win[rr][2].x, win[rr][2].y, win[rr][2].z, win[rr][2].w};
        #pragma unroll
        for (int i = 0; i < DD; ++i) {
            f32x4 o;
            o.x = lrelu(r.x * tw[i + 0]);
            o.y = lrelu(r.y * tw[i + 1]);
            o.z = lrelu(r.z * tw[i + 2]);
            o.w = lrelu(r.w * tw[i + 3]);
            *reinterpret_cast<f32x4*>(
                outb + (size_t)(i * DD + j) * HW + (size_t)y * W + x) = o;
        }
    }
}

__global__ __launch_bounds__(256) void corr_kernel(const float* __restrict__ ref,
                                                   const float* __restrict__ tgt,
                                                   float* __restrict__ out) {
    // grid = bc(256) * ysplit(8) * jhalf(2) = 4096 blocks
    const unsigned blk = blockIdx.x;
    const unsigned jh  = blk & 1u;
    const unsigned ysp = (blk >> 1) & 7u;
    const unsigned bc  = blk >> 4;

    const unsigned x4 = threadIdx.x & 31u;
    const unsigned y  = ysp * 8u + (threadIdx.x >> 5);

    const float* refp = ref + (size_t)bc * HW;
    const float* tgtp = tgt + (size_t)bc * HW;
    float* outb = out + (size_t)bc * (DD * DD * HW);

    if (jh == 0) run_half<0, 5>(refp, tgtp, outb, y, x4);
    else         run_half<5, 4>(refp, tgtp, outb, y, x4);
}

extern "C" void kernel_launch(void* const* d_in, const int* in_sizes, int n_in,
                              void* d_out, int out_size, void* d_ws, size_t ws_size,
                              hipStream_t stream) {
    const float* ref = (const float*)d_in[0];
    const float* tgt = (const float*)d_in[1];
    float* out = (float*)d_out;

    corr_kernel<<<B * C * 8 * 2, 256, 0, stream>>>(ref, tgt, out);
}